// Round 1
// baseline (566.149 us; speedup 1.0000x reference)
//
#include <hip/hip_runtime.h>
#include <hip/hip_bf16.h>
#include <stdint.h>

typedef unsigned short u16;
typedef __attribute__((ext_vector_type(4))) float f32x4;
typedef __attribute__((ext_vector_type(8))) short s16x8;

#define SEQ 2048
#define NB 4
#define DM 1024
#define NHD 16
#define DH 64

__device__ __forceinline__ u16 f2bf(float f) {
  union { float f; uint32_t u; } v; v.f = f;
  return (u16)((v.u + 0x7FFFu + ((v.u >> 16) & 1u)) >> 16);
}
__device__ __forceinline__ float bf2f(u16 u) {
  union { uint32_t u; float f; } v; v.u = ((uint32_t)u) << 16;
  return v.f;
}

// ---------- fp32 -> bf16 elementwise ----------
__global__ __launch_bounds__(256) void k_cvt(const float* __restrict__ in,
                                             u16* __restrict__ out, int n4) {
  int idx = blockIdx.x * 256 + threadIdx.x;
  int stride = gridDim.x * 256;
  for (; idx < n4; idx += stride) {
    float4 v = ((const float4*)in)[idx];
    ushort4 o;
    o.x = f2bf(v.x); o.y = f2bf(v.y); o.z = f2bf(v.z); o.w = f2bf(v.w);
    ((ushort4*)out)[idx] = o;
  }
}

// ---------- fp32 [R][C] -> bf16 transposed [C][R] ----------
__global__ __launch_bounds__(256) void k_tpose(const float* __restrict__ in,
                                               u16* __restrict__ out, int R, int C) {
  __shared__ u16 tile[64][65];
  int c0 = blockIdx.x * 64, r0 = blockIdx.y * 64;
  int tx = threadIdx.x & 63, ty = threadIdx.x >> 6;
  #pragma unroll
  for (int rr = ty; rr < 64; rr += 4)
    tile[rr][tx] = f2bf(in[(long)(r0 + rr) * C + c0 + tx]);
  __syncthreads();
  #pragma unroll
  for (int cc = ty; cc < 64; cc += 4)
    out[(long)(c0 + cc) * R + r0 + tx] = tile[tx][cc];
}

// ---------- bf16 GEMM: C[M][N] = A[M][K] @ B^T (B given as [N][K]) + bias ----------
// 128x128 tile, BK=32, 4 waves (2x2), each wave 64x64 via 4x4 MFMA 16x16x32.
template<int OUT_BF16>
__global__ __launch_bounds__(256) void k_gemm(const u16* __restrict__ A,
                                              const u16* __restrict__ Bt_g,
                                              const float* __restrict__ bias,
                                              void* __restrict__ Cout,
                                              int M, int N, int K) {
  constexpr int LP = 72;  // padded stride (ushorts): 144B rows, 16B-aligned, ~2-way banks
  __shared__ u16 As[128 * LP];
  __shared__ u16 Bs[128 * LP];
  int tid = threadIdx.x, lane = tid & 63, wave = tid >> 6;
  int wm = (wave >> 1) * 64, wn = (wave & 1) * 64;
  long m0 = (long)blockIdx.y * 128, n0 = (long)blockIdx.x * 128;
  int lrow = lane & 15, lk8 = (lane >> 4) * 8;
  f32x4 acc[4][4] = {};
  int sr = tid >> 2, sc = (tid & 3) * 8;
  for (int k0 = 0; k0 < K; k0 += 32) {
    __syncthreads();
    *(s16x8*)&As[sr * LP + sc]        = *(const s16x8*)&A[(m0 + sr) * K + k0 + sc];
    *(s16x8*)&As[(sr + 64) * LP + sc] = *(const s16x8*)&A[(m0 + sr + 64) * K + k0 + sc];
    *(s16x8*)&Bs[sr * LP + sc]        = *(const s16x8*)&Bt_g[(n0 + sr) * K + k0 + sc];
    *(s16x8*)&Bs[(sr + 64) * LP + sc] = *(const s16x8*)&Bt_g[(n0 + sr + 64) * K + k0 + sc];
    __syncthreads();
    s16x8 af[4], bfr[4];
    #pragma unroll
    for (int t = 0; t < 4; ++t) af[t]  = *(const s16x8*)&As[(wm + t * 16 + lrow) * LP + lk8];
    #pragma unroll
    for (int t = 0; t < 4; ++t) bfr[t] = *(const s16x8*)&Bs[(wn + t * 16 + lrow) * LP + lk8];
    #pragma unroll
    for (int i = 0; i < 4; ++i)
      #pragma unroll
      for (int j = 0; j < 4; ++j)
        acc[i][j] = __builtin_amdgcn_mfma_f32_16x16x32_bf16(af[i], bfr[j], acc[i][j], 0, 0, 0);
  }
  int crow = (lane >> 4) * 4, ccol = lane & 15;
  #pragma unroll
  for (int i = 0; i < 4; ++i)
  #pragma unroll
  for (int j = 0; j < 4; ++j) {
    long col = n0 + wn + j * 16 + ccol;
    float bv = bias ? bias[col] : 0.f;
    #pragma unroll
    for (int r = 0; r < 4; ++r) {
      long row = m0 + wm + i * 16 + crow + r;
      float v = acc[i][j][r] + bv;
      if (OUT_BF16) ((u16*)Cout)[row * N + col] = f2bf(v);
      else          ((float*)Cout)[row * N + col] = v;
    }
  }
}

// ---------- RoPE + scale + layout [B,S,3*Dm] -> [B*H, S, 64] ----------
__global__ __launch_bounds__(256) void k_rope(const u16* __restrict__ qkv,
                                              u16* __restrict__ Qr,
                                              u16* __restrict__ Kr,
                                              u16* __restrict__ Vr) {
  int t = blockIdx.x * 256 + threadIdx.x;  // B*S*H*32 threads
  int i = t & 31;
  int h = (t >> 5) & 15;
  int s = (t >> 9) & 2047;
  int b = t >> 20;
  long row = ((long)(b * SEQ + s)) * 3072 + h * 64;
  float q1 = bf2f(qkv[row + i]),        q2 = bf2f(qkv[row + i + 32]);
  float k1 = bf2f(qkv[row + 1024 + i]), k2 = bf2f(qkv[row + 1024 + i + 32]);
  u16 v1 = qkv[row + 2048 + i];
  u16 v2 = qkv[row + 2048 + i + 32];
  float fq = powf(10000.0f, -(float)i * 0.03125f);
  float ang = (float)s * fq;
  float c = cosf(ang), sn = sinf(ang);
  long ob = ((long)((b * NHD + h) * SEQ + s)) * 64;
  Qr[ob + i]      = f2bf((q1 * c - q2 * sn) * 0.125f);  // scale = Dh^-0.5 = 1/8 exact
  Qr[ob + i + 32] = f2bf((q2 * c + q1 * sn) * 0.125f);
  Kr[ob + i]      = f2bf(k1 * c - k2 * sn);
  Kr[ob + i + 32] = f2bf(k2 * c + k1 * sn);
  Vr[ob + i] = v1; Vr[ob + i + 32] = v2;
}

// ---------- causal attention: writes attn (f32, incl. zeros) + ctx (bf16) ----------
// block = (q-block of 64 rows) x (b,h); 4 waves x 16 q-rows.
// sweep1: row sums of exp(s); sweep2: p = exp(s)/l -> attn write + PV via LDS P tile.
__global__ __launch_bounds__(256) void k_attn(const u16* __restrict__ Qr,
                                              const u16* __restrict__ Kr,
                                              const u16* __restrict__ Vr,
                                              float* __restrict__ attn,
                                              u16* __restrict__ ctx) {
  constexpr int LP = 72;
  __shared__ u16 Ks[64 * LP];
  __shared__ u16 Vt[64 * LP];
  __shared__ u16 Ps[4][16 * LP];
  int tid = threadIdx.x, lane = tid & 63, wave = tid >> 6;
  int bh = blockIdx.y;
  int q0 = blockIdx.x * 64;
  int qw0 = q0 + wave * 16;
  int lrow = lane & 15, lg = lane >> 4, lk8 = lg * 8;
  const u16* Qb = Qr + (long)bh * SEQ * 64;
  const u16* Kb = Kr + (long)bh * SEQ * 64;
  const u16* Vb = Vr + (long)bh * SEQ * 64;
  float* attn_bh = attn + (long)bh * SEQ * SEQ;

  s16x8 qf0 = *(const s16x8*)&Qb[(long)(qw0 + lrow) * 64 + lk8];
  s16x8 qf1 = *(const s16x8*)&Qb[(long)(qw0 + lrow) * 64 + 32 + lk8];

  int njt = blockIdx.x + 1;          // k-tiles needed (causal)
  int str = tid >> 3, stc = (tid & 7) * 8;

  // ---- sweep 1: row sums of exp(score) ----
  float suml[4] = {0.f, 0.f, 0.f, 0.f};
  for (int jt = 0; jt < njt; ++jt) {
    long k0 = (long)jt * 64;
    __syncthreads();
    *(s16x8*)&Ks[str * LP + stc]        = *(const s16x8*)&Kb[(k0 + str) * 64 + stc];
    *(s16x8*)&Ks[(str + 32) * LP + stc] = *(const s16x8*)&Kb[(k0 + str + 32) * 64 + stc];
    __syncthreads();
    int ctmax = (jt < njt - 1) ? 3 : wave;
    for (int ct = 0; ct <= ctmax; ++ct) {
      f32x4 sa = {0.f, 0.f, 0.f, 0.f};
      s16x8 kf0 = *(const s16x8*)&Ks[(ct * 16 + lrow) * LP + lk8];
      s16x8 kf1 = *(const s16x8*)&Ks[(ct * 16 + lrow) * LP + 32 + lk8];
      sa = __builtin_amdgcn_mfma_f32_16x16x32_bf16(qf0, kf0, sa, 0, 0, 0);
      sa = __builtin_amdgcn_mfma_f32_16x16x32_bf16(qf1, kf1, sa, 0, 0, 0);
      bool diag = (jt == njt - 1) && (ct == wave);
      int gcol = (int)k0 + ct * 16 + lrow;
      #pragma unroll
      for (int r = 0; r < 4; ++r) {
        int grow = qw0 + lg * 4 + r;
        float e = (!diag || gcol <= grow) ? __expf(sa[r]) : 0.f;
        suml[r] += e;
      }
    }
  }
  #pragma unroll
  for (int r = 0; r < 4; ++r) {
    float v = suml[r];
    v += __shfl_xor(v, 1, 16);
    v += __shfl_xor(v, 2, 16);
    v += __shfl_xor(v, 4, 16);
    v += __shfl_xor(v, 8, 16);
    suml[r] = 1.0f / v;             // reciprocal row sum
  }

  // ---- sweep 2: normalized probs -> attn + PV ----
  f32x4 oacc[4] = {};
  for (int jt = 0; jt < njt; ++jt) {
    long k0 = (long)jt * 64;
    __syncthreads();
    *(s16x8*)&Ks[str * LP + stc]        = *(const s16x8*)&Kb[(k0 + str) * 64 + stc];
    *(s16x8*)&Ks[(str + 32) * LP + stc] = *(const s16x8*)&Kb[(k0 + str + 32) * 64 + stc];
    {
      s16x8 v0 = *(const s16x8*)&Vb[(k0 + str) * 64 + stc];
      s16x8 v1 = *(const s16x8*)&Vb[(k0 + str + 32) * 64 + stc];
      #pragma unroll
      for (int j = 0; j < 8; ++j) {
        Vt[(stc + j) * LP + str]      = (u16)v0[j];
        Vt[(stc + j) * LP + str + 32] = (u16)v1[j];
      }
    }
    __syncthreads();
    int ctmax = (jt < njt - 1) ? 3 : wave;
    u16* ps = &Ps[wave][0];
    #pragma unroll
    for (int ct = 0; ct < 4; ++ct) {
      int gcol = (int)k0 + ct * 16 + lrow;
      if (ct <= ctmax) {
        f32x4 sa = {0.f, 0.f, 0.f, 0.f};
        s16x8 kf0 = *(const s16x8*)&Ks[(ct * 16 + lrow) * LP + lk8];
        s16x8 kf1 = *(const s16x8*)&Ks[(ct * 16 + lrow) * LP + 32 + lk8];
        sa = __builtin_amdgcn_mfma_f32_16x16x32_bf16(qf0, kf0, sa, 0, 0, 0);
        sa = __builtin_amdgcn_mfma_f32_16x16x32_bf16(qf1, kf1, sa, 0, 0, 0);
        bool diag = (jt == njt - 1) && (ct == wave);
        #pragma unroll
        for (int r = 0; r < 4; ++r) {
          int grow = qw0 + lg * 4 + r;
          float e = (!diag || gcol <= grow) ? __expf(sa[r]) : 0.f;
          float p = e * suml[r];
          attn_bh[(long)grow * SEQ + gcol] = p;
          ps[(lg * 4 + r) * LP + ct * 16 + lrow] = f2bf(p);
        }
      } else {
        #pragma unroll
        for (int r = 0; r < 4; ++r) {
          int grow = qw0 + lg * 4 + r;
          attn_bh[(long)grow * SEQ + gcol] = 0.f;
          ps[(lg * 4 + r) * LP + ct * 16 + lrow] = 0;
        }
      }
    }
    // PV: O += P @ V  (A = P from LDS, B = V from transposed LDS)
    s16x8 pf0 = *(const s16x8*)&Ps[wave][lrow * LP + lk8];
    s16x8 pf1 = *(const s16x8*)&Ps[wave][lrow * LP + 32 + lk8];
    #pragma unroll
    for (int dt = 0; dt < 4; ++dt) {
      s16x8 vf0 = *(const s16x8*)&Vt[(dt * 16 + lrow) * LP + lk8];
      s16x8 vf1 = *(const s16x8*)&Vt[(dt * 16 + lrow) * LP + 32 + lk8];
      oacc[dt] = __builtin_amdgcn_mfma_f32_16x16x32_bf16(pf0, vf0, oacc[dt], 0, 0, 0);
      oacc[dt] = __builtin_amdgcn_mfma_f32_16x16x32_bf16(pf1, vf1, oacc[dt], 0, 0, 0);
    }
  }

  // ---- zero-fill columns beyond the q-block (pure write BW) ----
  {
    int cstart = q0 + 64;
    int zc4 = (SEQ - cstart) >> 2;
    float4 z = make_float4(0.f, 0.f, 0.f, 0.f);
    for (int row = 0; row < 64; ++row) {
      float* dst = &attn_bh[(long)(q0 + row) * SEQ + cstart];
      for (int cc = tid; cc < zc4; cc += 256)
        ((float4*)dst)[cc] = z;
    }
  }

  // ---- ctx write: [B*S][Dm] bf16 ----
  int b = bh >> 4, h = bh & 15;
  #pragma unroll
  for (int dt = 0; dt < 4; ++dt)
  #pragma unroll
  for (int r = 0; r < 4; ++r) {
    long grow = qw0 + lg * 4 + r;
    long col = h * 64 + dt * 16 + lrow;
    ctx[((long)b * SEQ + grow) * DM + col] = f2bf(oacc[dt][r]);
  }
}

extern "C" void kernel_launch(void* const* d_in, const int* in_sizes, int n_in,
                              void* d_out, int out_size, void* d_ws, size_t ws_size,
                              hipStream_t stream) {
  const float* x     = (const float*)d_in[0];
  const float* w_qkv = (const float*)d_in[1];
  const float* b_qkv = (const float*)d_in[2];
  const float* w_out = (const float*)d_in[3];
  const float* b_out = (const float*)d_in[4];
  float* outp = (float*)d_out;
  float* attn = outp + (long)NB * SEQ * DM;          // 8,388,608 floats in

  // workspace layout (69.2 MB needed): buffers that must survive k_attn
  char* ws = (char*)d_ws;
  u16* Qr  = (u16*)(ws);                 // 16,777,216 B
  u16* Kr  = (u16*)(ws + 16777216L);     // 16,777,216 B
  u16* Vr  = (u16*)(ws + 33554432L);     // 16,777,216 B
  u16* ctx = (u16*)(ws + 50331648L);     // 16,777,216 B
  u16* WoT = (u16*)(ws + 67108864L);     //  2,097,152 B  (w_out^T bf16 [1024][1024])

  // dead-before-k_attn scratch lives inside the attn output region (rewritten later)
  u16* qkvb = (u16*)attn;                              // 50,331,648 B  (bf16 qkv [8192][3072])
  u16* Xb   = (u16*)((char*)attn + 50331648L);         // 16,777,216 B  (bf16 x [8192][1024])
  u16* WqT  = (u16*)((char*)attn + 67108864L);         //  6,291,456 B  (w_qkv^T bf16 [3072][1024])

  k_cvt<<<1024, 256, 0, stream>>>(x, Xb, (NB * SEQ * DM) / 4);
  k_tpose<<<dim3(3 * DM / 64, DM / 64), 256, 0, stream>>>(w_qkv, WqT, DM, 3 * DM);
  k_tpose<<<dim3(DM / 64, DM / 64), 256, 0, stream>>>(w_out, WoT, DM, DM);

  // qkv = x @ w_qkv + b_qkv  -> bf16
  k_gemm<1><<<dim3(3 * DM / 128, NB * SEQ / 128), 256, 0, stream>>>(
      Xb, WqT, b_qkv, qkvb, NB * SEQ, 3 * DM, DM);

  // rope + scale + [B*H,S,64] layout
  k_rope<<<(NB * SEQ * NHD * 32) / 256, 256, 0, stream>>>(qkvb, Qr, Kr, Vr);

  // attention: writes full attn (f32) + ctx (bf16)
  k_attn<<<dim3(SEQ / 64, NB * NHD), 256, 0, stream>>>(Qr, Kr, Vr, attn, ctx);

  // out = ctx @ w_out + b_out -> f32
  k_gemm<0><<<dim3(DM / 128, NB * SEQ / 128), 256, 0, stream>>>(
      ctx, WoT, b_out, outp, NB * SEQ, DM, DM);
}